// Round 3
// baseline (13.758 us; speedup 1.0000x reference)
//
#include <hip/hip_runtime.h>

// POS extractor, algebraically collapsed:
//   h[b,w,l] = A_w*x0[t] + B_w*x1[t] + C_w*x2[t]   (t = w+l)
//   H[b,n]   = x0[n]*sum_w A_w + x1[n]*sum_w B_w + x2[n]*sum_w C_w
// over windows w in [n-L+1, n] ∩ [0, W).
// A_w = -2a/m0, B_w = (1+a)/m1, C_w = (a-1)/m2,
// a = sqrt(sumS0^2 / sumS1^2) from window cross-moments.
// mean-subtraction terms are analytically zero (rounding-level only).

constexpr int L_WIN = 48;                   // int(30*1.6)
constexpr int CHUNK = 256;                  // outputs per block
constexpr int NSAMP = CHUNK + 2 * L_WIN - 2;  // 350 staged samples
constexpr int NWIN  = CHUNK + L_WIN - 1;      // 303 windows per block
constexpr int BLOCK = 384;                  // 6 waves

__global__ __launch_bounds__(BLOCK)
void pos_kernel(const float* __restrict__ x, float* __restrict__ out,
                int B, int N) {
    const int W  = N - L_WIN;               // 8144 valid windows
    const int b  = blockIdx.y;
    const int n0 = blockIdx.x * CHUNK;
    const int t0 = n0 - (L_WIN - 1);        // first staged sample (may be <0)
    const int w0 = n0 - (L_WIN - 1);        // first window index (may be <0)

    __shared__ float sx[3][NSAMP];          // SoA channel samples
    __shared__ float sA[NWIN], sB[NWIN], sC[NWIN];

    const float* gx = x + (size_t)b * N * 3;
    const int tid = threadIdx.x;

    // ---- stage x into LDS (coalesced over the flat float range) ----
    for (int i = tid; i < 3 * NSAMP; i += BLOCK) {
        const int s = i / 3;
        const int c = i - 3 * s;
        const int t = t0 + s;
        float v = 0.0f;
        if (t >= 0 && t < N) v = gx[(size_t)3 * t + c];
        sx[c][s] = v;
    }
    __syncthreads();

    // ---- per-window coefficients ----
    for (int wl = tid; wl < NWIN; wl += BLOCK) {
        const int w = w0 + wl;
        float Ac = 0.0f, Bc = 0.0f, Cc = 0.0f;
        if (w >= 0 && w < W) {
            float s0 = 0.f, s1 = 0.f, s2 = 0.f;
            float p00 = 0.f, p11 = 0.f, p22 = 0.f;
            float p01 = 0.f, p02 = 0.f, p12 = 0.f;
            const int base = wl;            // w - t0 == wl
            #pragma unroll 8
            for (int l = 0; l < L_WIN; ++l) {
                const float a = sx[0][base + l];
                const float bm = sx[1][base + l];
                const float c = sx[2][base + l];
                s0 += a; s1 += bm; s2 += c;
                p00 = fmaf(a, a, p00);
                p11 = fmaf(bm, bm, p11);
                p22 = fmaf(c, c, p22);
                p01 = fmaf(a, bm, p01);
                p02 = fmaf(a, c, p02);
                p12 = fmaf(bm, c, p12);
            }
            const float q0 = (float)L_WIN / s0;   // 1/mean of channel 0
            const float q1 = (float)L_WIN / s1;
            const float q2 = (float)L_WIN / s2;
            // sum S0^2 = sum (Cn1 - Cn2)^2
            float ss0 = p11 * q1 * q1 - 2.f * p12 * q1 * q2 + p22 * q2 * q2;
            // sum S1^2 = sum (-2 Cn0 + Cn1 + Cn2)^2
            float ss1 = 4.f * p00 * q0 * q0 + p11 * q1 * q1 + p22 * q2 * q2
                      - 4.f * p01 * q0 * q1 - 4.f * p02 * q0 * q2
                      + 2.f * p12 * q1 * q2;
            ss0 = fmaxf(ss0, 0.0f);
            const float alpha = sqrtf(ss0 / ss1);  // ddof divisor cancels
            Ac = -2.0f * alpha * q0;
            Bc = (1.0f + alpha) * q1;
            Cc = (alpha - 1.0f) * q2;
        }
        sA[wl] = Ac; sB[wl] = Bc; sC[wl] = Cc;
    }
    __syncthreads();

    // ---- overlap-add collapsed to coefficient sliding sums ----
    for (int nl = tid; nl < CHUNK; nl += BLOCK) {
        const int n = n0 + nl;
        float SA = 0.f, SB = 0.f, SC = 0.f;
        #pragma unroll 8
        for (int k = 0; k < L_WIN; ++k) {
            SA += sA[nl + k];
            SB += sB[nl + k];
            SC += sC[nl + k];
        }
        const int sl = nl + (L_WIN - 1);    // t0 + sl == n
        const float x0v = sx[0][sl];
        const float x1v = sx[1][sl];
        const float x2v = sx[2][sl];
        out[(size_t)b * N + n] = x0v * SA + x1v * SB + x2v * SC;
    }
}

extern "C" void kernel_launch(void* const* d_in, const int* in_sizes, int n_in,
                              void* d_out, int out_size, void* d_ws, size_t ws_size,
                              hipStream_t stream) {
    const float* x = (const float*)d_in[0];
    float* out = (float*)d_out;
    const int B = 32;
    const int N = in_sizes[0] / (B * 3);    // 8192
    dim3 grid(N / CHUNK, B);
    pos_kernel<<<grid, BLOCK, 0, stream>>>(x, out, B, N);
}

// Round 4
// 9.634 us; speedup vs baseline: 1.4280x; 1.4280x over previous
//
#include <hip/hip_runtime.h>

// POS extractor, algebraically collapsed + prefix-sum sliding windows.
//
//   h[b,w,l] = A_w*x0[t] + B_w*x1[t] + C_w*x2[t]   (t = w+l)
//   H[b,n]   = x0[n]*SA[n] + x1[n]*SB[n] + x2[n]*SC[n],
//              SA[n] = sum_{w in [n-47,n] ∩ [0,W)} A_w  (etc.)
//
// Window coefficients from 9 cross-moments (sums of x_i and x_i*x_j over the
// 48-sample window), each moment computed as a difference of two prefix-sum
// reads. Coefficient sliding sums likewise via a second prefix pass.
// Mean-subtraction terms of the reference are analytically zero.

constexpr int L_WIN = 48;                     // int(30*1.6)
constexpr int CHUNK = 512;                    // outputs per block
constexpr int NSAMP = CHUNK + 2 * L_WIN - 2;  // 606 staged samples
constexpr int NWIN  = CHUNK + L_WIN - 1;      // 559 windows per block
constexpr int BLOCK = 576;                    // 9 waves -> one per Q array
constexpr int QLEN  = NSAMP + 1;              // 607 prefix entries
constexpr int QPAD  = 640;                    // 64 lanes * 10 elems
constexpr int PLEN  = NWIN + 1;               // 560 prefix entries
constexpr int PPAD  = 576;

// In-place exclusive-style prefix scan of a[0..len) by ONE full wave.
// Each lane owns 10 consecutive elements (sequential scan in regs), then a
// 6-step shfl_up wave scan combines lane totals. No cross-wave traffic.
__device__ __forceinline__ void wave_scan_inplace(float* a, int len) {
    const int lane = threadIdx.x & 63;
    const int base = lane * 10;
    float r[10];
    float run = 0.0f;
    #pragma unroll
    for (int j = 0; j < 10; ++j) {
        const int e = base + j;
        const float v = (e < len) ? a[e] : 0.0f;
        run += v;
        r[j] = run;                 // inclusive within lane
    }
    float incl = run;               // wave-level inclusive scan of lane sums
    #pragma unroll
    for (int d = 1; d < 64; d <<= 1) {
        const float v = __shfl_up(incl, d);
        if (lane >= d) incl += v;
    }
    const float excl = incl - run;  // sum of all lower lanes
    #pragma unroll
    for (int j = 0; j < 10; ++j) {
        const int e = base + j;
        if (e < len) a[e] = excl + r[j];
    }
}

__global__ __launch_bounds__(BLOCK)
void pos_kernel(const float* __restrict__ x, float* __restrict__ out,
                int B, int N) {
    const int W  = N - L_WIN;              // 8144 valid windows
    const int b  = blockIdx.y;
    const int n0 = blockIdx.x * CHUNK;
    const int t0 = n0 - (L_WIN - 1);       // first staged sample (may be <0)
    const int w0 = t0;                     // first window index  (may be <0)

    // Q[k][j] : after scan, exclusive prefix of product k over staged samples
    //   k = 0..2 : x0, x1, x2
    //   k = 3..5 : x0^2, x1^2, x2^2
    //   k = 6..8 : x0*x1, x0*x2, x1*x2
    __shared__ float Q[9][QPAD];
    __shared__ float PC[3][PPAD];          // prefix of window coeffs A,B,C

    const float* gx = x + (size_t)b * N * 3;
    const int tid = threadIdx.x;
    const int wid = tid >> 6;

    // ---- phase A: per-sample products -> LDS (coalesced global reads) ----
    for (int i = tid; i < NSAMP; i += BLOCK) {
        const int t = t0 + i;
        float x0 = 0.0f, x1 = 0.0f, x2 = 0.0f;
        if (t >= 0 && t < N) {             // OOB samples only feed invalid
            const float* p = gx + (size_t)3 * t;   // windows (coeffs forced 0)
            x0 = p[0]; x1 = p[1]; x2 = p[2];
        }
        Q[0][i + 1] = x0;       Q[1][i + 1] = x1;       Q[2][i + 1] = x2;
        Q[3][i + 1] = x0 * x0;  Q[4][i + 1] = x1 * x1;  Q[5][i + 1] = x2 * x2;
        Q[6][i + 1] = x0 * x1;  Q[7][i + 1] = x0 * x2;  Q[8][i + 1] = x1 * x2;
    }
    if (tid < 9) Q[tid][0] = 0.0f;
    __syncthreads();

    // ---- phase B: 9 prefix scans, one wave each ----
    wave_scan_inplace(&Q[wid][0], QLEN);   // wid in [0,9)
    __syncthreads();

    // ---- phase C: window coefficients (O(1) per window) ----
    for (int wl = tid; wl < NWIN; wl += BLOCK) {
        const int w = w0 + wl;
        float Ac = 0.0f, Bc = 0.0f, Cc = 0.0f;
        if (w >= 0 && w < W) {
            const float m0  = Q[0][wl + L_WIN] - Q[0][wl];
            const float m1  = Q[1][wl + L_WIN] - Q[1][wl];
            const float m2  = Q[2][wl + L_WIN] - Q[2][wl];
            const float p00 = Q[3][wl + L_WIN] - Q[3][wl];
            const float p11 = Q[4][wl + L_WIN] - Q[4][wl];
            const float p22 = Q[5][wl + L_WIN] - Q[5][wl];
            const float p01 = Q[6][wl + L_WIN] - Q[6][wl];
            const float p02 = Q[7][wl + L_WIN] - Q[7][wl];
            const float p12 = Q[8][wl + L_WIN] - Q[8][wl];
            const float q0 = (float)L_WIN / m0;    // 1/mean per channel
            const float q1 = (float)L_WIN / m1;
            const float q2 = (float)L_WIN / m2;
            // sum S0^2 = sum (Cn1 - Cn2)^2
            float ss0 = p11 * q1 * q1 - 2.f * p12 * q1 * q2 + p22 * q2 * q2;
            // sum S1^2 = sum (-2 Cn0 + Cn1 + Cn2)^2
            float ss1 = 4.f * p00 * q0 * q0 + p11 * q1 * q1 + p22 * q2 * q2
                      - 4.f * p01 * q0 * q1 - 4.f * p02 * q0 * q2
                      + 2.f * p12 * q1 * q2;
            ss0 = fmaxf(ss0, 0.0f);
            const float alpha = sqrtf(ss0 / ss1);  // ddof divisor cancels
            Ac = -2.0f * alpha * q0;
            Bc = (1.0f + alpha) * q1;
            Cc = (alpha - 1.0f) * q2;
        }
        PC[0][wl + 1] = Ac;
        PC[1][wl + 1] = Bc;
        PC[2][wl + 1] = Cc;
    }
    if (tid < 3) PC[tid][0] = 0.0f;
    __syncthreads();

    // ---- phase D: 3 prefix scans of the coefficient arrays ----
    if (wid < 3) wave_scan_inplace(&PC[wid][0], PLEN);
    __syncthreads();

    // ---- phase E: outputs (O(1) per output) ----
    for (int nl = tid; nl < CHUNK; nl += BLOCK) {
        const int n = n0 + nl;
        const float SA = PC[0][nl + L_WIN] - PC[0][nl];
        const float SB = PC[1][nl + L_WIN] - PC[1][nl];
        const float SC = PC[2][nl + L_WIN] - PC[2][nl];
        const float* p = gx + (size_t)3 * n;       // L1/L2-warm from phase A
        out[(size_t)b * N + n] = p[0] * SA + p[1] * SB + p[2] * SC;
    }
}

extern "C" void kernel_launch(void* const* d_in, const int* in_sizes, int n_in,
                              void* d_out, int out_size, void* d_ws, size_t ws_size,
                              hipStream_t stream) {
    const float* x = (const float*)d_in[0];
    float* out = (float*)d_out;
    const int B = 32;
    const int N = in_sizes[0] / (B * 3);   // 8192
    dim3 grid(N / CHUNK, B);               // 16 x 32 = 512 blocks
    pos_kernel<<<grid, BLOCK, 0, stream>>>(x, out, B, N);
}